// Round 11
// baseline (397.921 us; speedup 1.0000x reference)
//
#include <hip/hip_runtime.h>
#include <hip/hip_bf16.h>

#define NN 50000
#define NE 800000

typedef unsigned int u32;
typedef unsigned short u16;
typedef __attribute__((ext_vector_type(2))) _Float16 half2v;
typedef __attribute__((ext_vector_type(8))) _Float16 half8;
typedef __attribute__((ext_vector_type(4))) float f32x4;    // MFMA C/D

__device__ __forceinline__ float silu_f(float x) {
    return x * (1.0f / (1.0f + __expf(-x)));
}
__device__ __forceinline__ u16 f2h_bits(float f) {          // f32 -> f16 (HW RNE)
    union { _Float16 h; u16 u; } c; c.h = (_Float16)f; return c.u;
}
__device__ __forceinline__ _Float16 h_from_bits(u16 u) {
    union { u16 u; _Float16 h; } c; c.u = u; return c.h;
}
__device__ __forceinline__ float h2f(u16 u) {
    return (float)h_from_bits(u);
}

// ---------------------------------------------------------------------------
// Sort-by-DST machinery: histogram -> 2-level exclusive scan -> scatter ranks
// ---------------------------------------------------------------------------
__global__ __launch_bounds__(256) void k_hist(const int* __restrict__ ei, u32* __restrict__ cnt) {
    int e = blockIdx.x * 256 + threadIdx.x;
    atomicAdd(&cnt[ei[NE + e]], 1u);
}

__global__ __launch_bounds__(256) void k_scan_a(const u32* __restrict__ cnt, u32* __restrict__ part) {
    __shared__ u32 sb[256];
    int t = threadIdx.x, i = blockIdx.x * 256 + t;
    u32 v = (i < NN) ? cnt[i] : 0u;
    sb[t] = v; __syncthreads();
    for (int off = 128; off > 0; off >>= 1) { if (t < off) sb[t] += sb[t + off]; __syncthreads(); }
    if (t == 0) part[blockIdx.x] = sb[0];
}

__global__ __launch_bounds__(256) void k_scan_b(u32* __restrict__ part, int nparts) {
    __shared__ u32 sb[256];
    int t = threadIdx.x;
    u32 v = (t < nparts) ? part[t] : 0u;
    sb[t] = v; __syncthreads();
    for (int off = 1; off < 256; off <<= 1) {
        u32 x = (t >= off) ? sb[t - off] : 0u; __syncthreads();
        sb[t] += x; __syncthreads();
    }
    if (t < nparts) part[t] = sb[t] - v;          // exclusive
}

__global__ __launch_bounds__(256) void k_scan_c(const u32* __restrict__ cnt, const u32* __restrict__ part,
                                                u32* __restrict__ row, u32* __restrict__ rowcur) {
    __shared__ u32 sb[256];
    int t = threadIdx.x, i = blockIdx.x * 256 + t;
    u32 v = (i < NN) ? cnt[i] : 0u;
    sb[t] = v; __syncthreads();
    for (int off = 1; off < 256; off <<= 1) {
        u32 x = (t >= off) ? sb[t - off] : 0u; __syncthreads();
        sb[t] += x; __syncthreads();
    }
    if (i < NN) {
        u32 ex = part[blockIdx.x] + sb[t] - v;
        row[i] = ex; rowcur[i] = ex;
    }
    if (i == 0) row[NN] = NE;
}

__global__ __launch_bounds__(256) void k_scatter(const int* __restrict__ ei, u32* __restrict__ rowcur,
                                                 u32* __restrict__ rank, u32* __restrict__ ssrc,
                                                 u16* __restrict__ sdst) {
    int e = blockIdx.x * 256 + threadIdx.x;
    u32 s_ = (u32)ei[e];
    u32 d_ = (u32)ei[NE + e];
    u32 pos = atomicAdd(&rowcur[d_], 1u);
    rank[e] = pos;
    ssrc[pos] = s_;
    sdst[pos] = (u16)d_;
}

// ---------------------------------------------------------------------------
// feat f32 -> f16 copy: feat16[n][f] (6.4 MB, ~single-XCD-L2-resident)
// ---------------------------------------------------------------------------
__global__ __launch_bounds__(256) void k_feat16(const float* __restrict__ feat, u16* __restrict__ feat16) {
    int i = blockIdx.x * 256 + threadIdx.x;      // 400000 threads, 8 elems each
    const float* fp = feat + (size_t)i * 8;
    float4 v0 = *(const float4*)fp;
    float4 v1 = *(const float4*)(fp + 4);
    ushort4 o0{f2h_bits(v0.x), f2h_bits(v0.y), f2h_bits(v0.z), f2h_bits(v0.w)};
    ushort4 o1{f2h_bits(v1.x), f2h_bits(v1.y), f2h_bits(v1.z), f2h_bits(v1.w)};
    u16* op = feat16 + (size_t)i * 8;
    *(ushort4*)op = o0;
    *(ushort4*)(op + 4) = o1;
}

// ---------------------------------------------------------------------------
// Wt transpose: WtT[g][m*64+f] = f16(W_tp[f][m][g])   [64][576] f16
// ---------------------------------------------------------------------------
__global__ __launch_bounds__(256) void k_wt(const float* __restrict__ Wtp, u16* __restrict__ WtT) {
    int o = blockIdx.x * 256 + threadIdx.x;     // 0..36863
    int g = o / 576, k = o % 576;
    int m = k >> 6, f = k & 63;
    WtT[o] = f2h_bits(Wtp[f * 576 + m * 64 + g]);
}

// ---------------------------------------------------------------------------
// K1: per-edge weight MLP; writes s (f16, padded to 12) at dst-sorted pos.
// ---------------------------------------------------------------------------
__global__ __launch_bounds__(256) void k_edge_mlp(
    const float* __restrict__ edge_attr, const float* __restrict__ edge_sh,
    const float* __restrict__ W1, const float* __restrict__ b1,
    const float* __restrict__ W2, const float* __restrict__ b2,
    const u32* __restrict__ rank,
    u16* __restrict__ s_sorted)            // [NE][12] f16 at rank[e]
{
    __shared__ float sAttr[256 * 36];
    const int t  = threadIdx.x;
    const int e0 = blockIdx.x * 256;

    const float* ga = edge_attr + (size_t)e0 * 32;
    #pragma unroll
    for (int k = 0; k < 32; ++k) {
        int i = k * 256 + t;
        sAttr[(i >> 5) * 36 + (i & 31)] = ga[i];
    }
    __syncthreads();

    float a[32];
    #pragma unroll
    for (int q = 0; q < 8; ++q) {
        float4 v = *(const float4*)&sAttr[t * 36 + q * 4];
        a[4*q+0] = v.x; a[4*q+1] = v.y; a[4*q+2] = v.z; a[4*q+3] = v.w;
    }

    float hid[64];
    #pragma unroll
    for (int h = 0; h < 64; ++h) hid[h] = b1[h];
    for (int d = 0; d < 32; ++d) {
        const float ad = a[d];
        const float* wr = W1 + d * 64;
        #pragma unroll
        for (int h = 0; h < 64; ++h) hid[h] += ad * wr[h];
    }

    float w[9];
    #pragma unroll
    for (int m = 0; m < 9; ++m) w[m] = b2[m];
    for (int h = 0; h < 64; ++h) {
        const float hv = silu_f(hid[h]);
        const float* w2r = W2 + h * 9;
        #pragma unroll
        for (int m = 0; m < 9; ++m) w[m] += hv * w2r[m];
    }

    const size_t e = (size_t)e0 + t;
    const float* sh = edge_sh + e * 9;
    u16 sw[12];
    #pragma unroll
    for (int m = 0; m < 9; ++m) sw[m] = f2h_bits(sh[m] * w[m]);
    sw[9] = sw[10] = sw[11] = 0;

    u16* dp = s_sorted + (size_t)rank[e] * 12;
    ushort4 v0{sw[0], sw[1], sw[2],  sw[3]};
    ushort4 v1{sw[4], sw[5], sw[6],  sw[7]};
    ushort4 v2{sw[8], sw[9], sw[10], sw[11]};
    *(ushort4*)(dp + 0) = v0;
    *(ushort4*)(dp + 4) = v1;
    *(ushort4*)(dp + 8) = v2;
}

// ---------------------------------------------------------------------------
// K3: MFMA combine, f16 datapath.  Block = 256 dst-sorted edges, 4 waves.
// __launch_bounds__(256,2) => 128-VGPR cap, no spill (~115 live); LDS 34.8KB
// allows up to 4 blocks/CU.  Reduce: ALL-atomicAdd segmented form (r7/r8
// field-proven incl. graph-replay revalidation; r9/r10's plain-store interior
// optimization showed a schedule-sensitive post-timing divergence — reverted).
// ---------------------------------------------------------------------------
__global__ __launch_bounds__(256, 2) void k_combine_mfma(
    const u32* __restrict__ ssrc, const u16* __restrict__ sdst,
    const u32* __restrict__ row,  const u16* __restrict__ s_sorted,
    const u16* __restrict__ feat16, const u16* __restrict__ WtT,
    float* __restrict__ out)
{
    __shared__ u16 msg[256 * 68];          // f16 bits
    const int t  = threadIdx.x;
    const int w  = t >> 6;
    const int l  = t & 63;
    const int p0 = blockIdx.x * 256;
    const int rbase = w << 6;

    // ---- hoisted: srcs, then 8 independent 16B feat gathers, then s ----
    u32 srcr[4];
    #pragma unroll
    for (int et = 0; et < 4; ++et)
        srcr[et] = ssrc[p0 + rbase + (et << 4) + (l & 15)];

    half8 h16[4][2];                        // [et][fhalf]
    #pragma unroll
    for (int et = 0; et < 4; ++et)
        #pragma unroll
        for (int fh = 0; fh < 2; ++fh)
            h16[et][fh] = *(const half8*)(feat16 +
                (size_t)srcr[et] * 64 + (fh << 5) + ((l >> 4) << 3));

    half2v s2[4][9];                        // {s,s} pairs
    #pragma unroll
    for (int et = 0; et < 4; ++et) {
        const u16* sp = s_sorted + (size_t)(p0 + rbase + (et << 4) + (l & 15)) * 12;
        #pragma unroll
        for (int m = 0; m < 9; ++m) {
            _Float16 sv = h_from_bits(sp[m]);
            s2[et][m] = half2v{sv, sv};
        }
    }

    f32x4 acc[4][4] = {};
    #pragma unroll
    for (int fhalf = 0; fhalf < 2; ++fhalf) {
        #pragma unroll
        for (int m = 0; m < 9; ++m) {
            const int tt = (m << 1) + fhalf;          // K-slice: k = tt*32 ..
            half8 bfr[4];
            #pragma unroll
            for (int gt = 0; gt < 4; ++gt)
                bfr[gt] = *(const half8*)(WtT +
                    (size_t)(((gt << 4) + (l & 15)) * 576 + tt * 32 + ((l >> 4) << 3)));
            #pragma unroll
            for (int et = 0; et < 4; ++et) {
                union { half2v h2[4]; half8 v; } A;
                const union { half8 v; half2v h2[4]; } H = { h16[et][fhalf] };
                A.h2[0] = H.h2[0] * s2[et][m];         // v_pk_mul_f16
                A.h2[1] = H.h2[1] * s2[et][m];
                A.h2[2] = H.h2[2] * s2[et][m];
                A.h2[3] = H.h2[3] * s2[et][m];
                #pragma unroll
                for (int gt = 0; gt < 4; ++gt)
                    acc[et][gt] = __builtin_amdgcn_mfma_f32_16x16x32_f16(A.v, bfr[gt], acc[et][gt], 0, 0, 0);
            }
        }
    }

    // ---- C tiles -> LDS msg[256][68] f16 (disjoint cells) ----
    #pragma unroll
    for (int et = 0; et < 4; ++et)
        #pragma unroll
        for (int gt = 0; gt < 4; ++gt)
            #pragma unroll
            for (int rg = 0; rg < 4; ++rg) {
                int rloc = rbase + (et << 4) + ((l >> 4) << 2) + rg;   // C row = edge
                int col  = (gt << 4) + (l & 15);                       // C col = g
                msg[rloc * 68 + col] = f2h_bits(acc[et][gt][rg]);
            }
    __syncthreads();

    // ---- segmented per-node reduction; one atomic per (node,g) per block ----
    const int dfirst = sdst[p0];
    const int dlast  = sdst[p0 + 255];
    for (int n = dfirst + w; n <= dlast; n += 4) {
        int a = (int)row[n]     - p0; if (a < 0)   a = 0;
        int b = (int)row[n + 1] - p0; if (b > 256) b = 256;
        if (a < b) {
            float v = 0.f;
            for (int p = a; p < b; ++p) v += h2f(msg[p * 68 + l]);
            atomicAdd(out + (size_t)n * 64 + l, v * 0.25f);    // 1/sqrt(16)
        }
    }
}

// ---------------------------------------------------------------------------
// K4: FiLM, in-place on d_out.
// ---------------------------------------------------------------------------
__global__ __launch_bounds__(256) void k_film(
    const float* __restrict__ c_noise,
    const float* __restrict__ Wn1, const float* __restrict__ bn1,
    const float* __restrict__ Wn2, const float* __restrict__ bn2,
    float* __restrict__ out)
{
    const int n    = (blockIdx.x * 256 + threadIdx.x) >> 6;
    const int lane = threadIdx.x & 63;
    const float c  = c_noise[n];
    const float hid = silu_f(fmaf(c, Wn1[lane], bn1[lane]));
    float g = bn2[lane], b = bn2[64 + lane];
    for (int h = 0; h < 64; ++h) {
        const float hv = __shfl(hid, h, 64);
        g = fmaf(hv, Wn2[h * 128 + lane],      g);
        b = fmaf(hv, Wn2[h * 128 + 64 + lane], b);
    }
    const size_t i = (size_t)n * 64 + lane;
    out[i] = fmaf(out[i], 1.f + g, b);
}

// ---------------------------------------------------------------------------
extern "C" void kernel_launch(void* const* d_in, const int* in_sizes, int n_in,
                              void* d_out, int out_size, void* d_ws, size_t ws_size,
                              hipStream_t stream) {
    const float* features   = (const float*)d_in[0];
    const int*   edge_index = (const int*)  d_in[1];
    const float* edge_attr  = (const float*)d_in[2];
    const float* edge_sh    = (const float*)d_in[3];
    const float* c_noise    = (const float*)d_in[4];
    const float* W1  = (const float*)d_in[5];
    const float* b1  = (const float*)d_in[6];
    const float* W2  = (const float*)d_in[7];
    const float* b2  = (const float*)d_in[8];
    const float* Wtp = (const float*)d_in[9];
    const float* Wn1 = (const float*)d_in[10];
    const float* bn1 = (const float*)d_in[11];
    const float* Wn2 = (const float*)d_in[12];
    const float* bn2 = (const float*)d_in[13];
    float* out = (float*)d_out;

    char* ws = (char*)d_ws;
    u16* feat16   = (u16*)(ws);                    //  6,400,000 B
    u16* s_sorted = (u16*)(ws +  6400000);         // 19,200,000 B
    u32* ssrc     = (u32*)(ws + 25600000);         //  3,200,000 B
    u32* rank     = (u32*)(ws + 28800000);         //  3,200,000 B
    u16* sdst     = (u16*)(ws + 32000000);         //  1,600,000 B
    u32* row      = (u32*)(ws + 33600000);         //    200,016 B (NN+1)
    u32* rowcur   = (u32*)(ws + 33800016);         //    200,000 B
    u32* cnt      = (u32*)(ws + 34000016);         //    200,000 B
    u32* part     = (u32*)(ws + 34200016);         //      1,024 B
    u16* WtT      = (u16*)(ws + 34201040);         //     73,728 B  (end ~34.3 MB)

    const int nparts = (NN + 255) / 256;           // 196

    hipMemsetAsync(cnt, 0, (size_t)NN * 4, stream);
    hipMemsetAsync(out, 0, (size_t)NN * 64 * sizeof(float), stream);

    k_hist   <<<NE / 256, 256, 0, stream>>>(edge_index, cnt);
    k_scan_a <<<nparts, 256, 0, stream>>>(cnt, part);
    k_scan_b <<<1, 256, 0, stream>>>(part, nparts);
    k_scan_c <<<nparts, 256, 0, stream>>>(cnt, part, row, rowcur);
    k_scatter<<<NE / 256, 256, 0, stream>>>(edge_index, rowcur, rank, ssrc, sdst);

    k_feat16  <<<(NN * 64 / 8 + 255) / 256, 256, 0, stream>>>(features, feat16);
    k_wt      <<<(576 * 64) / 256, 256, 0, stream>>>(Wtp, WtT);
    k_edge_mlp<<<NE / 256, 256, 0, stream>>>(edge_attr, edge_sh, W1, b1, W2, b2, rank, s_sorted);

    k_combine_mfma<<<NE / 256, 256, 0, stream>>>(ssrc, sdst, row, s_sorted,
                                                 feat16, WtT, out);

    k_film<<<(NN * 64) / 256, 256, 0, stream>>>(c_noise, Wn1, bn1, Wn2, bn2, out);
}

// Round 12
// 333.794 us; speedup vs baseline: 1.1921x; 1.1921x over previous
//
#include <hip/hip_runtime.h>
#include <hip/hip_bf16.h>

#define NN 50000
#define NE 800000

typedef unsigned int u32;
typedef unsigned short u16;
typedef __attribute__((ext_vector_type(2))) _Float16 half2v;
typedef __attribute__((ext_vector_type(8))) _Float16 half8;
typedef __attribute__((ext_vector_type(4))) float f32x4;    // MFMA C/D

__device__ __forceinline__ float silu_f(float x) {
    return x * (1.0f / (1.0f + __expf(-x)));
}
__device__ __forceinline__ u16 f2h_bits(float f) {          // f32 -> f16 (HW RNE)
    union { _Float16 h; u16 u; } c; c.h = (_Float16)f; return c.u;
}
__device__ __forceinline__ _Float16 h_from_bits(u16 u) {
    union { u16 u; _Float16 h; } c; c.u = u; return c.h;
}
__device__ __forceinline__ float h2f(u16 u) {
    return (float)h_from_bits(u);
}

// ---------------------------------------------------------------------------
// Sort-by-DST machinery: histogram -> 2-level exclusive scan -> scatter ranks
// ---------------------------------------------------------------------------
__global__ __launch_bounds__(256) void k_hist(const int* __restrict__ ei, u32* __restrict__ cnt) {
    int e = blockIdx.x * 256 + threadIdx.x;
    atomicAdd(&cnt[ei[NE + e]], 1u);
}

__global__ __launch_bounds__(256) void k_scan_a(const u32* __restrict__ cnt, u32* __restrict__ part) {
    __shared__ u32 sb[256];
    int t = threadIdx.x, i = blockIdx.x * 256 + t;
    u32 v = (i < NN) ? cnt[i] : 0u;
    sb[t] = v; __syncthreads();
    for (int off = 128; off > 0; off >>= 1) { if (t < off) sb[t] += sb[t + off]; __syncthreads(); }
    if (t == 0) part[blockIdx.x] = sb[0];
}

__global__ __launch_bounds__(256) void k_scan_b(u32* __restrict__ part, int nparts) {
    __shared__ u32 sb[256];
    int t = threadIdx.x;
    u32 v = (t < nparts) ? part[t] : 0u;
    sb[t] = v; __syncthreads();
    for (int off = 1; off < 256; off <<= 1) {
        u32 x = (t >= off) ? sb[t - off] : 0u; __syncthreads();
        sb[t] += x; __syncthreads();
    }
    if (t < nparts) part[t] = sb[t] - v;          // exclusive
}

__global__ __launch_bounds__(256) void k_scan_c(const u32* __restrict__ cnt, const u32* __restrict__ part,
                                                u32* __restrict__ row, u32* __restrict__ rowcur) {
    __shared__ u32 sb[256];
    int t = threadIdx.x, i = blockIdx.x * 256 + t;
    u32 v = (i < NN) ? cnt[i] : 0u;
    sb[t] = v; __syncthreads();
    for (int off = 1; off < 256; off <<= 1) {
        u32 x = (t >= off) ? sb[t - off] : 0u; __syncthreads();
        sb[t] += x; __syncthreads();
    }
    if (i < NN) {
        u32 ex = part[blockIdx.x] + sb[t] - v;
        row[i] = ex; rowcur[i] = ex;
    }
    if (i == 0) row[NN] = NE;
}

__global__ __launch_bounds__(256) void k_scatter(const int* __restrict__ ei, u32* __restrict__ rowcur,
                                                 u32* __restrict__ rank, u32* __restrict__ ssrc,
                                                 u16* __restrict__ sdst) {
    int e = blockIdx.x * 256 + threadIdx.x;
    u32 s_ = (u32)ei[e];
    u32 d_ = (u32)ei[NE + e];
    u32 pos = atomicAdd(&rowcur[d_], 1u);
    rank[e] = pos;
    ssrc[pos] = s_;
    sdst[pos] = (u16)d_;
}

// ---------------------------------------------------------------------------
// feat f32 -> f16 copy: feat16[n][f] (6.4 MB)
// ---------------------------------------------------------------------------
__global__ __launch_bounds__(256) void k_feat16(const float* __restrict__ feat, u16* __restrict__ feat16) {
    int i = blockIdx.x * 256 + threadIdx.x;      // 400000 threads, 8 elems each
    const float* fp = feat + (size_t)i * 8;
    float4 v0 = *(const float4*)fp;
    float4 v1 = *(const float4*)(fp + 4);
    ushort4 o0{f2h_bits(v0.x), f2h_bits(v0.y), f2h_bits(v0.z), f2h_bits(v0.w)};
    ushort4 o1{f2h_bits(v1.x), f2h_bits(v1.y), f2h_bits(v1.z), f2h_bits(v1.w)};
    u16* op = feat16 + (size_t)i * 8;
    *(ushort4*)op = o0;
    *(ushort4*)(op + 4) = o1;
}

// ---------------------------------------------------------------------------
// Wt transpose: WtT[g][m*64+f] = f16(W_tp[f][m][g])   [64][576] f16
// ---------------------------------------------------------------------------
__global__ __launch_bounds__(256) void k_wt(const float* __restrict__ Wtp, u16* __restrict__ WtT) {
    int o = blockIdx.x * 256 + threadIdx.x;     // 0..36863
    int g = o / 576, k = o % 576;
    int m = k >> 6, f = k & 63;
    WtT[o] = f2h_bits(Wtp[f * 576 + m * 64 + g]);
}

// ---------------------------------------------------------------------------
// K1: per-edge weight MLP; writes s (f16, padded to 12) at dst-sorted pos.
// ---------------------------------------------------------------------------
__global__ __launch_bounds__(256) void k_edge_mlp(
    const float* __restrict__ edge_attr, const float* __restrict__ edge_sh,
    const float* __restrict__ W1, const float* __restrict__ b1,
    const float* __restrict__ W2, const float* __restrict__ b2,
    const u32* __restrict__ rank,
    u16* __restrict__ s_sorted)            // [NE][12] f16 at rank[e]
{
    __shared__ float sAttr[256 * 36];
    const int t  = threadIdx.x;
    const int e0 = blockIdx.x * 256;

    const float* ga = edge_attr + (size_t)e0 * 32;
    #pragma unroll
    for (int k = 0; k < 32; ++k) {
        int i = k * 256 + t;
        sAttr[(i >> 5) * 36 + (i & 31)] = ga[i];
    }
    __syncthreads();

    float a[32];
    #pragma unroll
    for (int q = 0; q < 8; ++q) {
        float4 v = *(const float4*)&sAttr[t * 36 + q * 4];
        a[4*q+0] = v.x; a[4*q+1] = v.y; a[4*q+2] = v.z; a[4*q+3] = v.w;
    }

    float hid[64];
    #pragma unroll
    for (int h = 0; h < 64; ++h) hid[h] = b1[h];
    for (int d = 0; d < 32; ++d) {
        const float ad = a[d];
        const float* wr = W1 + d * 64;
        #pragma unroll
        for (int h = 0; h < 64; ++h) hid[h] += ad * wr[h];
    }

    float w[9];
    #pragma unroll
    for (int m = 0; m < 9; ++m) w[m] = b2[m];
    for (int h = 0; h < 64; ++h) {
        const float hv = silu_f(hid[h]);
        const float* w2r = W2 + h * 9;
        #pragma unroll
        for (int m = 0; m < 9; ++m) w[m] += hv * w2r[m];
    }

    const size_t e = (size_t)e0 + t;
    const float* sh = edge_sh + e * 9;
    u16 sw[12];
    #pragma unroll
    for (int m = 0; m < 9; ++m) sw[m] = f2h_bits(sh[m] * w[m]);
    sw[9] = sw[10] = sw[11] = 0;

    u16* dp = s_sorted + (size_t)rank[e] * 12;
    ushort4 v0{sw[0], sw[1], sw[2],  sw[3]};
    ushort4 v1{sw[4], sw[5], sw[6],  sw[7]};
    ushort4 v2{sw[8], sw[9], sw[10], sw[11]};
    *(ushort4*)(dp + 0) = v0;
    *(ushort4*)(dp + 4) = v1;
    *(ushort4*)(dp + 8) = v2;
}

// ---------------------------------------------------------------------------
// K3: MFMA combine, f16 datapath, LDS-staged B operand.
// Block = 256 dst-sorted edges, 4 waves.  WtT[64][576] staged once per block
// into LDS [64][584] (row stride 1168 B: dword-stride ≡ 4 mod 32 => a wave's
// 64x16B ds_read_b128 partitions all 32 banks at the inherent 8 lanes/bank).
// The K-loop is then LDS+VALU+MFMA only — no in-loop global latency.
// LDS region union'd with msg (WtT dead after MFMA loop; barrier between).
// Reduce: ALL-atomicAdd segmented form (replay-proven r7/r8/r11).
// ---------------------------------------------------------------------------
union SmU {
    u16 wt[64 * 584];      // 74,752 B  (staged WtT, padded rows)
    u16 msg[256 * 68];     // 34,816 B  (C spill, f16)
};

__global__ __launch_bounds__(256, 2) void k_combine_mfma(
    const u32* __restrict__ ssrc, const u16* __restrict__ sdst,
    const u32* __restrict__ row,  const u16* __restrict__ s_sorted,
    const u16* __restrict__ feat16, const u16* __restrict__ WtT,
    float* __restrict__ out)
{
    __shared__ SmU sm;
    const int t  = threadIdx.x;
    const int w  = t >> 6;
    const int l  = t & 63;
    const int p0 = blockIdx.x * 256;
    const int rbase = w << 6;

    // ---- hoisted global loads: srcs, 8 feat gathers, s ----
    u32 srcr[4];
    #pragma unroll
    for (int et = 0; et < 4; ++et)
        srcr[et] = ssrc[p0 + rbase + (et << 4) + (l & 15)];

    half8 h16[4][2];                        // [et][fhalf]
    #pragma unroll
    for (int et = 0; et < 4; ++et)
        #pragma unroll
        for (int fh = 0; fh < 2; ++fh)
            h16[et][fh] = *(const half8*)(feat16 +
                (size_t)srcr[et] * 64 + (fh << 5) + ((l >> 4) << 3));

    half2v s2[4][9];                        // {s,s} pairs
    #pragma unroll
    for (int et = 0; et < 4; ++et) {
        const u16* sp = s_sorted + (size_t)(p0 + rbase + (et << 4) + (l & 15)) * 12;
        #pragma unroll
        for (int m = 0; m < 9; ++m) {
            _Float16 sv = h_from_bits(sp[m]);
            s2[et][m] = half2v{sv, sv};
        }
    }

    // ---- stage WtT [64][576] -> LDS [64][584] in 16B chunks ----
    {
        const uint4* gsrc = (const uint4*)WtT;         // [64*72] 16B chunks
        uint4* lw = (uint4*)sm.wt;                     // 584/8 = 73 chunks/row
        #pragma unroll
        for (int i = 0; i < 18; ++i) {
            int c = i * 256 + t;                       // 0..4607
            int r = c / 72, q = c - r * 72;
            lw[r * 73 + q] = gsrc[c];
        }
    }
    __syncthreads();

    f32x4 acc[4][4] = {};
    #pragma unroll
    for (int fhalf = 0; fhalf < 2; ++fhalf) {
        #pragma unroll
        for (int m = 0; m < 9; ++m) {
            const int tt = (m << 1) + fhalf;          // K-slice: k = tt*32 ..
            half8 bfr[4];
            #pragma unroll
            for (int gt = 0; gt < 4; ++gt)
                bfr[gt] = *(const half8*)&sm.wt[
                    (((gt << 4) + (l & 15)) * 584) + tt * 32 + ((l >> 4) << 3)];
            #pragma unroll
            for (int et = 0; et < 4; ++et) {
                union { half2v h2[4]; half8 v; } A;
                const union { half8 v; half2v h2[4]; } H = { h16[et][fhalf] };
                A.h2[0] = H.h2[0] * s2[et][m];         // v_pk_mul_f16
                A.h2[1] = H.h2[1] * s2[et][m];
                A.h2[2] = H.h2[2] * s2[et][m];
                A.h2[3] = H.h2[3] * s2[et][m];
                #pragma unroll
                for (int gt = 0; gt < 4; ++gt)
                    acc[et][gt] = __builtin_amdgcn_mfma_f32_16x16x32_f16(A.v, bfr[gt], acc[et][gt], 0, 0, 0);
            }
        }
    }
    __syncthreads();   // all B-reads done before msg overwrites the union

    // ---- C tiles -> LDS msg[256][68] f16 (disjoint cells) ----
    #pragma unroll
    for (int et = 0; et < 4; ++et)
        #pragma unroll
        for (int gt = 0; gt < 4; ++gt)
            #pragma unroll
            for (int rg = 0; rg < 4; ++rg) {
                int rloc = rbase + (et << 4) + ((l >> 4) << 2) + rg;   // C row = edge
                int col  = (gt << 4) + (l & 15);                       // C col = g
                sm.msg[rloc * 68 + col] = f2h_bits(acc[et][gt][rg]);
            }
    __syncthreads();

    // ---- segmented per-node reduction; one atomic per (node,g) per block ----
    const int dfirst = sdst[p0];
    const int dlast  = sdst[p0 + 255];
    for (int n = dfirst + w; n <= dlast; n += 4) {
        int a = (int)row[n]     - p0; if (a < 0)   a = 0;
        int b = (int)row[n + 1] - p0; if (b > 256) b = 256;
        if (a < b) {
            float v = 0.f;
            for (int p = a; p < b; ++p) v += h2f(sm.msg[p * 68 + l]);
            atomicAdd(out + (size_t)n * 64 + l, v * 0.25f);    // 1/sqrt(16)
        }
    }
}

// ---------------------------------------------------------------------------
// K4: FiLM, in-place on d_out.
// ---------------------------------------------------------------------------
__global__ __launch_bounds__(256) void k_film(
    const float* __restrict__ c_noise,
    const float* __restrict__ Wn1, const float* __restrict__ bn1,
    const float* __restrict__ Wn2, const float* __restrict__ bn2,
    float* __restrict__ out)
{
    const int n    = (blockIdx.x * 256 + threadIdx.x) >> 6;
    const int lane = threadIdx.x & 63;
    const float c  = c_noise[n];
    const float hid = silu_f(fmaf(c, Wn1[lane], bn1[lane]));
    float g = bn2[lane], b = bn2[64 + lane];
    for (int h = 0; h < 64; ++h) {
        const float hv = __shfl(hid, h, 64);
        g = fmaf(hv, Wn2[h * 128 + lane],      g);
        b = fmaf(hv, Wn2[h * 128 + 64 + lane], b);
    }
    const size_t i = (size_t)n * 64 + lane;
    out[i] = fmaf(out[i], 1.f + g, b);
}

// ---------------------------------------------------------------------------
extern "C" void kernel_launch(void* const* d_in, const int* in_sizes, int n_in,
                              void* d_out, int out_size, void* d_ws, size_t ws_size,
                              hipStream_t stream) {
    const float* features   = (const float*)d_in[0];
    const int*   edge_index = (const int*)  d_in[1];
    const float* edge_attr  = (const float*)d_in[2];
    const float* edge_sh    = (const float*)d_in[3];
    const float* c_noise    = (const float*)d_in[4];
    const float* W1  = (const float*)d_in[5];
    const float* b1  = (const float*)d_in[6];
    const float* W2  = (const float*)d_in[7];
    const float* b2  = (const float*)d_in[8];
    const float* Wtp = (const float*)d_in[9];
    const float* Wn1 = (const float*)d_in[10];
    const float* bn1 = (const float*)d_in[11];
    const float* Wn2 = (const float*)d_in[12];
    const float* bn2 = (const float*)d_in[13];
    float* out = (float*)d_out;

    char* ws = (char*)d_ws;
    u16* feat16   = (u16*)(ws);                    //  6,400,000 B
    u16* s_sorted = (u16*)(ws +  6400000);         // 19,200,000 B
    u32* ssrc     = (u32*)(ws + 25600000);         //  3,200,000 B
    u32* rank     = (u32*)(ws + 28800000);         //  3,200,000 B
    u16* sdst     = (u16*)(ws + 32000000);         //  1,600,000 B
    u32* row      = (u32*)(ws + 33600000);         //    200,016 B (NN+1)
    u32* rowcur   = (u32*)(ws + 33800016);         //    200,000 B
    u32* cnt      = (u32*)(ws + 34000016);         //    200,000 B
    u32* part     = (u32*)(ws + 34200016);         //      1,024 B
    u16* WtT      = (u16*)(ws + 34201040);         //     73,728 B  (end ~34.3 MB)

    const int nparts = (NN + 255) / 256;           // 196

    hipMemsetAsync(cnt, 0, (size_t)NN * 4, stream);
    hipMemsetAsync(out, 0, (size_t)NN * 64 * sizeof(float), stream);

    k_hist   <<<NE / 256, 256, 0, stream>>>(edge_index, cnt);
    k_scan_a <<<nparts, 256, 0, stream>>>(cnt, part);
    k_scan_b <<<1, 256, 0, stream>>>(part, nparts);
    k_scan_c <<<nparts, 256, 0, stream>>>(cnt, part, row, rowcur);
    k_scatter<<<NE / 256, 256, 0, stream>>>(edge_index, rowcur, rank, ssrc, sdst);

    k_feat16  <<<(NN * 64 / 8 + 255) / 256, 256, 0, stream>>>(features, feat16);
    k_wt      <<<(576 * 64) / 256, 256, 0, stream>>>(Wtp, WtT);
    k_edge_mlp<<<NE / 256, 256, 0, stream>>>(edge_attr, edge_sh, W1, b1, W2, b2, rank, s_sorted);

    k_combine_mfma<<<NE / 256, 256, 0, stream>>>(ssrc, sdst, row, s_sorted,
                                                 feat16, WtT, out);

    k_film<<<(NN * 64) / 256, 256, 0, stream>>>(c_noise, Wn1, bn1, Wn2, bn2, out);
}

// Round 14
// 299.116 us; speedup vs baseline: 1.3303x; 1.1159x over previous
//
#include <hip/hip_runtime.h>
#include <hip/hip_bf16.h>

#define NN 50000
#define NE 800000

typedef unsigned int u32;
typedef unsigned short u16;
typedef __attribute__((ext_vector_type(2))) _Float16 half2v;
typedef __attribute__((ext_vector_type(8))) _Float16 half8;
typedef __attribute__((ext_vector_type(4))) float f32x4;    // MFMA C/D

__device__ __forceinline__ float silu_f(float x) {
    return x * (1.0f / (1.0f + __expf(-x)));
}
__device__ __forceinline__ u16 f2h_bits(float f) {          // f32 -> f16 (HW RNE)
    union { _Float16 h; u16 u; } c; c.h = (_Float16)f; return c.u;
}
__device__ __forceinline__ _Float16 h_from_bits(u16 u) {
    union { u16 u; _Float16 h; } c; c.u = u; return c.h;
}
__device__ __forceinline__ float h2f(u16 u) {
    return (float)h_from_bits(u);
}

// ---------------------------------------------------------------------------
// Sort-by-DST machinery: histogram -> 2-level exclusive scan -> scatter ranks
// ---------------------------------------------------------------------------
__global__ __launch_bounds__(256) void k_hist(const int* __restrict__ ei, u32* __restrict__ cnt) {
    int e = blockIdx.x * 256 + threadIdx.x;
    atomicAdd(&cnt[ei[NE + e]], 1u);
}

__global__ __launch_bounds__(256) void k_scan_a(const u32* __restrict__ cnt, u32* __restrict__ part) {
    __shared__ u32 sb[256];
    int t = threadIdx.x, i = blockIdx.x * 256 + t;
    u32 v = (i < NN) ? cnt[i] : 0u;
    sb[t] = v; __syncthreads();
    for (int off = 128; off > 0; off >>= 1) { if (t < off) sb[t] += sb[t + off]; __syncthreads(); }
    if (t == 0) part[blockIdx.x] = sb[0];
}

__global__ __launch_bounds__(256) void k_scan_b(u32* __restrict__ part, int nparts) {
    __shared__ u32 sb[256];
    int t = threadIdx.x;
    u32 v = (t < nparts) ? part[t] : 0u;
    sb[t] = v; __syncthreads();
    for (int off = 1; off < 256; off <<= 1) {
        u32 x = (t >= off) ? sb[t - off] : 0u; __syncthreads();
        sb[t] += x; __syncthreads();
    }
    if (t < nparts) part[t] = sb[t] - v;          // exclusive
}

__global__ __launch_bounds__(256) void k_scan_c(const u32* __restrict__ cnt, const u32* __restrict__ part,
                                                u32* __restrict__ row, u32* __restrict__ rowcur) {
    __shared__ u32 sb[256];
    int t = threadIdx.x, i = blockIdx.x * 256 + t;
    u32 v = (i < NN) ? cnt[i] : 0u;
    sb[t] = v; __syncthreads();
    for (int off = 1; off < 256; off <<= 1) {
        u32 x = (t >= off) ? sb[t - off] : 0u; __syncthreads();
        sb[t] += x; __syncthreads();
    }
    if (i < NN) {
        u32 ex = part[blockIdx.x] + sb[t] - v;
        row[i] = ex; rowcur[i] = ex;
    }
    if (i == 0) row[NN] = NE;
}

__global__ __launch_bounds__(256) void k_scatter(const int* __restrict__ ei, u32* __restrict__ rowcur,
                                                 u32* __restrict__ rank, u32* __restrict__ ssrc,
                                                 u16* __restrict__ sdst) {
    int e = blockIdx.x * 256 + threadIdx.x;
    u32 s_ = (u32)ei[e];
    u32 d_ = (u32)ei[NE + e];
    u32 pos = atomicAdd(&rowcur[d_], 1u);
    rank[e] = pos;
    ssrc[pos] = s_;
    sdst[pos] = (u16)d_;
}

// ---------------------------------------------------------------------------
// feat f32 -> f16 copy: feat16[n][f] (6.4 MB)
// ---------------------------------------------------------------------------
__global__ __launch_bounds__(256) void k_feat16(const float* __restrict__ feat, u16* __restrict__ feat16) {
    int i = blockIdx.x * 256 + threadIdx.x;      // 400000 threads, 8 elems each
    const float* fp = feat + (size_t)i * 8;
    float4 v0 = *(const float4*)fp;
    float4 v1 = *(const float4*)(fp + 4);
    ushort4 o0{f2h_bits(v0.x), f2h_bits(v0.y), f2h_bits(v0.z), f2h_bits(v0.w)};
    ushort4 o1{f2h_bits(v1.x), f2h_bits(v1.y), f2h_bits(v1.z), f2h_bits(v1.w)};
    u16* op = feat16 + (size_t)i * 8;
    *(ushort4*)op = o0;
    *(ushort4*)(op + 4) = o1;
}

// ---------------------------------------------------------------------------
// Weight preps (f16):
//   WtT[g][m*64+f] = W_tp[f][m][g]          [64][576]
//   W1T[h][d]      = W1[d][h]               [64][32]
//   W2T[n][h]      = (n<9) ? W2[h][n] : 0   [16][64]
// ---------------------------------------------------------------------------
__global__ __launch_bounds__(256) void k_wt(const float* __restrict__ Wtp, u16* __restrict__ WtT) {
    int o = blockIdx.x * 256 + threadIdx.x;     // 0..36863
    int g = o / 576, k = o % 576;
    int m = k >> 6, f = k & 63;
    WtT[o] = f2h_bits(Wtp[f * 576 + m * 64 + g]);
}

__global__ __launch_bounds__(256) void k_w1t(const float* __restrict__ W1, u16* __restrict__ W1T) {
    int o = blockIdx.x * 256 + threadIdx.x;     // 0..2047
    int n = o >> 5, k = o & 31;
    W1T[o] = f2h_bits(W1[k * 64 + n]);
}

__global__ __launch_bounds__(256) void k_w2t(const float* __restrict__ W2, u16* __restrict__ W2T) {
    int o = blockIdx.x * 256 + threadIdx.x;     // 0..1023
    int n = o >> 6, k = o & 63;
    W2T[o] = (n < 9) ? f2h_bits(W2[k * 9 + n]) : (u16)0;
}

// ---------------------------------------------------------------------------
// K1: per-edge weight MLP via MFMA.  Block = 256 edges (original order),
// 4 waves x 64 edges.  GEMM1: attr16[256x32] @ W1T -> hid (+b1, silu);
// per-wave LDS transpose; GEMM2: hid[256x64] @ W2T[16x64] (+b2);
// LDS roundtrip back to thread-per-edge; proven sh-mul + rank-store tail.
// r13 bug: W1T staging loop ran 2048 u32 but W1T is 1024 u32 ([64][32] f16)
// -> LDS overrun smashed sW2/sHid.  Fixed: i < 4.
// ---------------------------------------------------------------------------
__global__ __launch_bounds__(256, 2) void k_edge_mlp(
    const float* __restrict__ edge_attr, const float* __restrict__ edge_sh,
    const u16* __restrict__ W1T, const u16* __restrict__ W2T,
    const float* __restrict__ b1, const float* __restrict__ b2,
    const u32* __restrict__ rank,
    u16* __restrict__ s_sorted)            // [NE][12] f16 at rank[e]
{
    __shared__ u16 sW1[64 * 36];           //  4,608 B (pad 32->36: 18 dw, 2-way)
    __shared__ u16 sW2[16 * 68];           //  2,176 B
    __shared__ u16 sHid[4][64 * 68];       // 34,816 B (per-wave)
    __shared__ u16 sWout[256 * 12];        //  6,144 B
    const int t  = threadIdx.x;
    const int w  = t >> 6;
    const int l  = t & 63;
    const int e0 = blockIdx.x * 256;
    const int wbase = w << 6;

    // ---- stage W1T (1024 u32) + W2T (512 u32) into LDS ----
    {
        const u32* g1 = (const u32*)W1T;
        u32* l1 = (u32*)sW1;
        #pragma unroll
        for (int i = 0; i < 4; ++i) {              // 1024 u32 total (FIXED)
            int idx = i * 256 + t;                 // 0..1023
            int r = idx >> 4, c = idx & 15;        // 16 u32 per src row
            l1[r * 18 + c] = g1[idx];
        }
        const u32* g2 = (const u32*)W2T;
        u32* l2 = (u32*)sW2;
        #pragma unroll
        for (int i = 0; i < 2; ++i) {
            int idx = i * 256 + t;                 // 0..511
            int r = idx >> 5, c = idx & 31;        // 32 u32 per src row
            l2[r * 34 + c] = g2[idx];
        }
    }

    // ---- A-frags: attr rows -> f16 (8 contig k per lane) ----
    half8 aA[4];
    #pragma unroll
    for (int et = 0; et < 4; ++et) {
        const int e = e0 + wbase + (et << 4) + (l & 15);
        const float* ap = edge_attr + (size_t)e * 32 + ((l >> 4) << 3);
        float4 v0 = *(const float4*)ap;
        float4 v1 = *(const float4*)(ap + 4);
        aA[et] = half8{(_Float16)v0.x, (_Float16)v0.y, (_Float16)v0.z, (_Float16)v0.w,
                       (_Float16)v1.x, (_Float16)v1.y, (_Float16)v1.z, (_Float16)v1.w};
    }
    __syncthreads();

    // ---- GEMM1: [256x32] @ [32x64], K=32 (one MFMA per tile) ----
    f32x4 acc1[4][4] = {};
    {
        half8 bB[4];
        #pragma unroll
        for (int nt = 0; nt < 4; ++nt)
            bB[nt] = *(const half8*)&sW1[((nt << 4) + (l & 15)) * 36 + ((l >> 4) << 3)];
        #pragma unroll
        for (int et = 0; et < 4; ++et)
            #pragma unroll
            for (int nt = 0; nt < 4; ++nt)
                acc1[et][nt] = __builtin_amdgcn_mfma_f32_16x16x32_f16(aA[et], bB[nt], acc1[et][nt], 0, 0, 0);
    }

    // ---- +b1, silu, -> per-wave LDS hid tile [64][68] f16 ----
    {
        float b1v[4];
        #pragma unroll
        for (int nt = 0; nt < 4; ++nt) b1v[nt] = b1[(nt << 4) + (l & 15)];
        #pragma unroll
        for (int et = 0; et < 4; ++et)
            #pragma unroll
            for (int nt = 0; nt < 4; ++nt)
                #pragma unroll
                for (int rg = 0; rg < 4; ++rg) {
                    int r = (et << 4) + ((l >> 4) << 2) + rg;
                    int c = (nt << 4) + (l & 15);
                    sHid[w][r * 68 + c] = f2h_bits(silu_f(acc1[et][nt][rg] + b1v[nt]));
                }
    }
    __syncthreads();

    // ---- GEMM2: [256x64] @ [64x16], K=64 (2 K-slices) ----
    f32x4 acc2[4] = {};
    #pragma unroll
    for (int tt = 0; tt < 2; ++tt) {
        half8 b2f = *(const half8*)&sW2[(l & 15) * 68 + tt * 32 + ((l >> 4) << 3)];
        #pragma unroll
        for (int et = 0; et < 4; ++et) {
            half8 a2 = *(const half8*)&sHid[w][((et << 4) + (l & 15)) * 68 + tt * 32 + ((l >> 4) << 3)];
            acc2[et] = __builtin_amdgcn_mfma_f32_16x16x32_f16(a2, b2f, acc2[et], 0, 0, 0);
        }
    }

    // ---- +b2 -> LDS w tile [256][12] (cols 0..8) ----
    {
        const int m = l & 15;
        if (m < 9) {
            const float b2v = b2[m];
            #pragma unroll
            for (int et = 0; et < 4; ++et)
                #pragma unroll
                for (int rg = 0; rg < 4; ++rg) {
                    int r = wbase + (et << 4) + ((l >> 4) << 2) + rg;
                    sWout[r * 12 + m] = f2h_bits(acc2[et][rg] + b2v);
                }
        }
    }
    __syncthreads();

    // ---- proven tail: thread t = edge e0+t; s = sh * w; store at rank[e] ----
    const size_t e = (size_t)e0 + t;
    const float* sh = edge_sh + e * 9;
    u16 sw[12];
    #pragma unroll
    for (int m = 0; m < 9; ++m) sw[m] = f2h_bits(sh[m] * h2f(sWout[t * 12 + m]));
    sw[9] = sw[10] = sw[11] = 0;

    u16* dp = s_sorted + (size_t)rank[e] * 12;
    ushort4 v0{sw[0], sw[1], sw[2],  sw[3]};
    ushort4 v1{sw[4], sw[5], sw[6],  sw[7]};
    ushort4 v2{sw[8], sw[9], sw[10], sw[11]};
    *(ushort4*)(dp + 0) = v0;
    *(ushort4*)(dp + 4) = v1;
    *(ushort4*)(dp + 8) = v2;
}

// ---------------------------------------------------------------------------
// K3: MFMA combine, f16 datapath, LDS-staged B operand (r12-proven).
// ---------------------------------------------------------------------------
union SmU {
    u16 wt[64 * 584];      // 74,752 B  (staged WtT, padded rows)
    u16 msg[256 * 68];     // 34,816 B  (C spill, f16)
};

__global__ __launch_bounds__(256, 2) void k_combine_mfma(
    const u32* __restrict__ ssrc, const u16* __restrict__ sdst,
    const u32* __restrict__ row,  const u16* __restrict__ s_sorted,
    const u16* __restrict__ feat16, const u16* __restrict__ WtT,
    float* __restrict__ out)
{
    __shared__ SmU sm;
    const int t  = threadIdx.x;
    const int w  = t >> 6;
    const int l  = t & 63;
    const int p0 = blockIdx.x * 256;
    const int rbase = w << 6;

    // ---- hoisted global loads: srcs, 8 feat gathers, s ----
    u32 srcr[4];
    #pragma unroll
    for (int et = 0; et < 4; ++et)
        srcr[et] = ssrc[p0 + rbase + (et << 4) + (l & 15)];

    half8 h16[4][2];                        // [et][fhalf]
    #pragma unroll
    for (int et = 0; et < 4; ++et)
        #pragma unroll
        for (int fh = 0; fh < 2; ++fh)
            h16[et][fh] = *(const half8*)(feat16 +
                (size_t)srcr[et] * 64 + (fh << 5) + ((l >> 4) << 3));

    half2v s2[4][9];                        // {s,s} pairs
    #pragma unroll
    for (int et = 0; et < 4; ++et) {
        const u16* sp = s_sorted + (size_t)(p0 + rbase + (et << 4) + (l & 15)) * 12;
        #pragma unroll
        for (int m = 0; m < 9; ++m) {
            _Float16 sv = h_from_bits(sp[m]);
            s2[et][m] = half2v{sv, sv};
        }
    }

    // ---- stage WtT [64][576] -> LDS [64][584] in 16B chunks ----
    {
        const uint4* gsrc = (const uint4*)WtT;         // [64*72] 16B chunks
        uint4* lw = (uint4*)sm.wt;                     // 584/8 = 73 chunks/row
        #pragma unroll
        for (int i = 0; i < 18; ++i) {
            int c = i * 256 + t;                       // 0..4607
            int r = c / 72, q = c - r * 72;
            lw[r * 73 + q] = gsrc[c];
        }
    }
    __syncthreads();

    f32x4 acc[4][4] = {};
    #pragma unroll
    for (int fhalf = 0; fhalf < 2; ++fhalf) {
        #pragma unroll
        for (int m = 0; m < 9; ++m) {
            const int tt = (m << 1) + fhalf;          // K-slice: k = tt*32 ..
            half8 bfr[4];
            #pragma unroll
            for (int gt = 0; gt < 4; ++gt)
                bfr[gt] = *(const half8*)&sm.wt[
                    (((gt << 4) + (l & 15)) * 584) + tt * 32 + ((l >> 4) << 3)];
            #pragma unroll
            for (int et = 0; et < 4; ++et) {
                union { half2v h2[4]; half8 v; } A;
                const union { half8 v; half2v h2[4]; } H = { h16[et][fhalf] };
                A.h2[0] = H.h2[0] * s2[et][m];         // v_pk_mul_f16
                A.h2[1] = H.h2[1] * s2[et][m];
                A.h2[2] = H.h2[2] * s2[et][m];
                A.h2[3] = H.h2[3] * s2[et][m];
                #pragma unroll
                for (int gt = 0; gt < 4; ++gt)
                    acc[et][gt] = __builtin_amdgcn_mfma_f32_16x16x32_f16(A.v, bfr[gt], acc[et][gt], 0, 0, 0);
            }
        }
    }
    __syncthreads();   // all B-reads done before msg overwrites the union

    // ---- C tiles -> LDS msg[256][68] f16 (disjoint cells) ----
    #pragma unroll
    for (int et = 0; et < 4; ++et)
        #pragma unroll
        for (int gt = 0; gt < 4; ++gt)
            #pragma unroll
            for (int rg = 0; rg < 4; ++rg) {
                int rloc = rbase + (et << 4) + ((l >> 4) << 2) + rg;   // C row = edge
                int col  = (gt << 4) + (l & 15);                       // C col = g
                sm.msg[rloc * 68 + col] = f2h_bits(acc[et][gt][rg]);
            }
    __syncthreads();

    // ---- segmented per-node reduction; one atomic per (node,g) per block ----
    const int dfirst = sdst[p0];
    const int dlast  = sdst[p0 + 255];
    for (int n = dfirst + w; n <= dlast; n += 4) {
        int a = (int)row[n]     - p0; if (a < 0)   a = 0;
        int b = (int)row[n + 1] - p0; if (b > 256) b = 256;
        if (a < b) {
            float v = 0.f;
            for (int p = a; p < b; ++p) v += h2f(sm.msg[p * 68 + l]);
            atomicAdd(out + (size_t)n * 64 + l, v * 0.25f);    // 1/sqrt(16)
        }
    }
}

// ---------------------------------------------------------------------------
// K4: FiLM, in-place on d_out.
// ---------------------------------------------------------------------------
__global__ __launch_bounds__(256) void k_film(
    const float* __restrict__ c_noise,
    const float* __restrict__ Wn1, const float* __restrict__ bn1,
    const float* __restrict__ Wn2, const float* __restrict__ bn2,
    float* __restrict__ out)
{
    const int n    = (blockIdx.x * 256 + threadIdx.x) >> 6;
    const int lane = threadIdx.x & 63;
    const float c  = c_noise[n];
    const float hid = silu_f(fmaf(c, Wn1[lane], bn1[lane]));
    float g = bn2[lane], b = bn2[64 + lane];
    for (int h = 0; h < 64; ++h) {
        const float hv = __shfl(hid, h, 64);
        g = fmaf(hv, Wn2[h * 128 + lane],      g);
        b = fmaf(hv, Wn2[h * 128 + 64 + lane], b);
    }
    const size_t i = (size_t)n * 64 + lane;
    out[i] = fmaf(out[i], 1.f + g, b);
}

// ---------------------------------------------------------------------------
extern "C" void kernel_launch(void* const* d_in, const int* in_sizes, int n_in,
                              void* d_out, int out_size, void* d_ws, size_t ws_size,
                              hipStream_t stream) {
    const float* features   = (const float*)d_in[0];
    const int*   edge_index = (const int*)  d_in[1];
    const float* edge_attr  = (const float*)d_in[2];
    const float* edge_sh    = (const float*)d_in[3];
    const float* c_noise    = (const float*)d_in[4];
    const float* W1  = (const float*)d_in[5];
    const float* b1  = (const float*)d_in[6];
    const float* W2  = (const float*)d_in[7];
    const float* b2  = (const float*)d_in[8];
    const float* Wtp = (const float*)d_in[9];
    const float* Wn1 = (const float*)d_in[10];
    const float* bn1 = (const float*)d_in[11];
    const float* Wn2 = (const float*)d_in[12];
    const float* bn2 = (const float*)d_in[13];
    float* out = (float*)d_out;

    char* ws = (char*)d_ws;
    u16* feat16   = (u16*)(ws);                    //  6,400,000 B
    u16* s_sorted = (u16*)(ws +  6400000);         // 19,200,000 B
    u32* ssrc     = (u32*)(ws + 25600000);         //  3,200,000 B
    u32* rank     = (u32*)(ws + 28800000);         //  3,200,000 B
    u16* sdst     = (u16*)(ws + 32000000);         //  1,600,000 B
    u32* row      = (u32*)(ws + 33600000);         //    200,016 B (NN+1)
    u32* rowcur   = (u32*)(ws + 33800016);         //    200,000 B
    u32* cnt      = (u32*)(ws + 34000016);         //    200,000 B
    u32* part     = (u32*)(ws + 34200016);         //      1,024 B
    u16* WtT      = (u16*)(ws + 34201040);         //     73,728 B
    u16* W1T      = (u16*)(ws + 34274768);         //      4,096 B
    u16* W2T      = (u16*)(ws + 34278864);         //      2,048 B  (end ~34.3 MB)

    const int nparts = (NN + 255) / 256;           // 196

    hipMemsetAsync(cnt, 0, (size_t)NN * 4, stream);
    hipMemsetAsync(out, 0, (size_t)NN * 64 * sizeof(float), stream);

    k_hist   <<<NE / 256, 256, 0, stream>>>(edge_index, cnt);
    k_scan_a <<<nparts, 256, 0, stream>>>(cnt, part);
    k_scan_b <<<1, 256, 0, stream>>>(part, nparts);
    k_scan_c <<<nparts, 256, 0, stream>>>(cnt, part, row, rowcur);
    k_scatter<<<NE / 256, 256, 0, stream>>>(edge_index, rowcur, rank, ssrc, sdst);

    k_feat16  <<<(NN * 64 / 8 + 255) / 256, 256, 0, stream>>>(features, feat16);
    k_wt      <<<(576 * 64) / 256, 256, 0, stream>>>(Wtp, WtT);
    k_w1t     <<<8, 256, 0, stream>>>(W1, W1T);
    k_w2t     <<<4, 256, 0, stream>>>(W2, W2T);

    k_edge_mlp<<<NE / 256, 256, 0, stream>>>(edge_attr, edge_sh, W1T, W2T, b1, b2,
                                             rank, s_sorted);

    k_combine_mfma<<<NE / 256, 256, 0, stream>>>(ssrc, sdst, row, s_sorted,
                                                 feat16, WtT, out);

    k_film<<<(NN * 64) / 256, 256, 0, stream>>>(c_noise, Wn1, bn1, Wn2, bn2, out);
}